// Round 1
// baseline (1954.007 us; speedup 1.0000x reference)
//
#include <hip/hip_runtime.h>
#include <hip/hip_bf16.h>

#define B_ 64
#define S_ 2048
#define T_ 256

typedef _Float16 half2_t __attribute__((ext_vector_type(2)));

__device__ __forceinline__ float fdot2f(half2_t a, half2_t b, float c) {
#if __has_builtin(__builtin_amdgcn_fdot2)
  return __builtin_amdgcn_fdot2(a, b, c, false);
#else
  return c + (float)a.x * (float)b.x + (float)a.y * (float)b.y;
#endif
}

// Raw barrier: LDS-visibility only (lgkmcnt(0)), leaves global loads (vmcnt) in flight.
__device__ __forceinline__ void wg_barrier() {
  __builtin_amdgcn_sched_barrier(0);
  asm volatile("s_waitcnt lgkmcnt(0)" ::: "memory");
  __builtin_amdgcn_s_barrier();
  asm volatile("" ::: "memory");
  __builtin_amdgcn_sched_barrier(0);
}

// ---------------- numerator score: ws[b] ----------------
__global__ void crf_score(const float* __restrict__ em, const int* __restrict__ tags,
                          const int* __restrict__ mask, const float* __restrict__ trans,
                          const float* __restrict__ startt, const float* __restrict__ endt,
                          float* __restrict__ ws) {
  const int b = blockIdx.x;
  const int t = threadIdx.x;  // 256
  const int* tg = tags + b * S_;
  const int* mk = mask + b * S_;
  const float* eb = em + (size_t)b * S_ * T_;

  float sc = 0.f;
  int msum = 0;
  for (int s = t; s < S_; s += 256) {
    const int tag = tg[s];
    const int m = mk[s];
    msum += m;
    const float e = eb[(size_t)s * T_ + tag];
    if (s == 0) {
      sc += startt[tag] + e;  // emit at s=0 is unmasked in the reference
    } else {
      const int pt = tg[s - 1];
      sc += (trans[tag * T_ + pt] + e) * (float)m;  // transitions[tag_s, tag_{s-1}]
    }
  }
#pragma unroll
  for (int off = 32; off > 0; off >>= 1) {
    sc += __shfl_down(sc, off);
    msum += __shfl_down(msum, off);
  }
  __shared__ float ssc[4];
  __shared__ int smc[4];
  const int wv = t >> 6, ln = t & 63;
  if (ln == 0) { ssc[wv] = sc; smc[wv] = msum; }
  __syncthreads();
  if (t == 0) {
    const float s4 = (ssc[0] + ssc[1]) + (ssc[2] + ssc[3]);
    const int m4 = smc[0] + smc[1] + smc[2] + smc[3];
    const int last = tg[m4 - 1];
    ws[b] = s4 + endt[last];
  }
}

// ---------------- forward algorithm (log Z): ws[64+b] ----------------
// 512 threads: thread (j = tid>>1, p = tid&1) owns output column j, i-half p.
// W column-half in 64 half2 VGPRs; alpha (linear, renormalized) as 128 half2 in LDS.
__global__ __launch_bounds__(512, 2) void crf_forward(
    const float* __restrict__ em, const float* __restrict__ trans,
    const float* __restrict__ startt, const float* __restrict__ endt,
    float* __restrict__ ws) {
  const int b = blockIdx.x;
  const int tid = threadIdx.x;
  const int j = tid >> 1;
  const int p = tid & 1;
  const int wv = tid >> 6;  // wave id 0..7
  const float* eb = em + (size_t)b * S_ * T_;

  __shared__ __align__(16) half2_t aPak[T_ / 2];      // a packed in i-pairs
  __shared__ __align__(16) float ebuf[2][8][T_];      // emission chunks (8 rows each)
  __shared__ float wred[8];

  // --- one-time: W fragment into registers: w2[r] = (e^T[p*128+2r][j], e^T[p*128+2r+1][j])
  half2_t w2[64];
#pragma unroll
  for (int r = 0; r < 64; ++r) {
    const int i0 = p * 128 + 2 * r;
    const float x0 = __expf(trans[i0 * T_ + j]);
    const float x1 = __expf(trans[(i0 + 1) * T_ + j]);
    half2_t h; h.x = (_Float16)x0; h.y = (_Float16)x1;
    w2[r] = h;
  }

  // --- init: alpha0 = start + em[0,:], normalize by max
  const float al0 = startt[j] + eb[j];
  float vm = al0;
#pragma unroll
  for (int off = 2; off <= 32; off <<= 1) vm = fmaxf(vm, __shfl_xor(vm, off));
  if ((tid & 63) == 0) wred[wv] = vm;
  __syncthreads();
  float m0 = wred[0];
#pragma unroll
  for (int k = 1; k < 8; ++k) m0 = fmaxf(m0, wred[k]);
  float c_run = m0;
  float u = __expf(al0 - m0);
  {
    const float u2 = __shfl_xor(u, 2);
    if ((tid & 3) == 0) { half2_t h; h.x = (_Float16)u; h.y = (_Float16)u2; aPak[j >> 1] = h; }
  }
  // prologue: stage chunk 0 (rows 1..8) into ebuf[0]
  const int col = (tid & 63) * 4;
  {
    const float4 f = *(const float4*)(eb + (size_t)(1 + wv) * T_ + col);
    *(float4*)&ebuf[0][wv][col] = f;
  }
  __syncthreads();
  // prefetch chunk 1 (rows 9..16) into registers
  float4 pre = *(const float4*)(eb + (size_t)(9 + wv) * T_ + col);

  int cur = 0;
  float u_last = u;
  for (int s = 1; s < S_; ++s) {
    const int sc = (s - 1) & 7;
    // ---- dot phase: z[j] = sum_i a[i] * W[i][j]  (fp16 inputs, fp32 accum)
    float c0 = 0.f, c1 = 0.f, c2 = 0.f, c3 = 0.f;
    const float4* af = (const float4*)(aPak + p * 64);
#pragma unroll
    for (int q = 0; q < 16; ++q) {
      const float4 blk = af[q];
      c0 = fdot2f(__builtin_bit_cast(half2_t, blk.x), w2[4 * q + 0], c0);
      c1 = fdot2f(__builtin_bit_cast(half2_t, blk.y), w2[4 * q + 1], c1);
      c2 = fdot2f(__builtin_bit_cast(half2_t, blk.z), w2[4 * q + 2], c2);
      c3 = fdot2f(__builtin_bit_cast(half2_t, blk.w), w2[4 * q + 3], c3);
    }
    const float acc = (c0 + c1) + (c2 + c3);
    const float z = acc + __shfl_xor(acc, 1);       // combine i-halves (both lanes get z)
    const float E = __expf(ebuf[cur][sc][j]);
    const float v = z * E;
    // ---- wave max (pairs already equal -> start at mask 2)
    float vmx = v;
#pragma unroll
    for (int off = 2; off <= 32; off <<= 1) vmx = fmaxf(vmx, __shfl_xor(vmx, off));
    if ((tid & 63) == 0) wred[wv] = vmx;
    wg_barrier();  // B1: wmax visible; all dot-phase reads of aPak/ebuf done
    float m = wred[0];
#pragma unroll
    for (int k = 1; k < 8; ++k) m = fmaxf(m, wred[k]);
    const float rin = __builtin_amdgcn_rcpf(m);
    c_run -= __logf(rin);       // exact bookkeeping for whatever rcp returned
    const float un = v * rin;   // in (0,1]: safe for fp16
    u_last = un;
    const float un2 = __shfl_xor(un, 2);
    if ((tid & 3) == 0) { half2_t h; h.x = (_Float16)un; h.y = (_Float16)un2; aPak[j >> 1] = h; }
    // ---- chunk staging on last slot of each chunk
    if (sc == 7) {
      const int nxt = cur ^ 1;
      *(float4*)&ebuf[nxt][wv][col] = pre;  // compiler inserts vmcnt wait for pre
      const int ck2 = ((s - 1) >> 3) + 2;
      if (ck2 < S_ / 8) {
        int row = 1 + ck2 * 8 + wv;
        if (row > S_ - 1) row = S_ - 1;  // last chunk tail: clamp (slot never read)
        pre = *(const float4*)(eb + (size_t)row * T_ + col);
      }
      cur = nxt;
    }
    wg_barrier();  // B2: aPak (and staged chunk) visible for next step
  }

  // ---- epilogue: log_z = c + log(sum_j a[j] * exp(end[j]))
  float fin = (p == 0) ? u_last * __expf(endt[j]) : 0.f;
#pragma unroll
  for (int off = 1; off <= 32; off <<= 1) fin += __shfl_xor(fin, off);
  if ((tid & 63) == 0) wred[wv] = fin;
  __syncthreads();
  if (tid == 0) {
    float tot = 0.f;
#pragma unroll
    for (int k = 0; k < 8; ++k) tot += wred[k];
    ws[64 + b] = c_run + __logf(tot);
  }
}

// ---------------- final: mean_b(score - logZ) ----------------
__global__ void crf_final(const float* __restrict__ ws, float* __restrict__ out) {
  const int t = threadIdx.x;  // 64
  float v = ws[t] - ws[64 + t];
#pragma unroll
  for (int off = 1; off <= 32; off <<= 1) v += __shfl_xor(v, off);
  if (t == 0) out[0] = v * (1.0f / 64.0f);
}

extern "C" void kernel_launch(void* const* d_in, const int* in_sizes, int n_in,
                              void* d_out, int out_size, void* d_ws, size_t ws_size,
                              hipStream_t stream) {
  const float* em = (const float*)d_in[0];
  const int* tags = (const int*)d_in[1];
  const int* mask = (const int*)d_in[2];
  const float* trans = (const float*)d_in[3];
  const float* startt = (const float*)d_in[4];
  const float* endt = (const float*)d_in[5];
  float* out = (float*)d_out;
  float* ws = (float*)d_ws;

  crf_score<<<B_, 256, 0, stream>>>(em, tags, mask, trans, startt, endt, ws);
  crf_forward<<<B_, 512, 0, stream>>>(em, trans, startt, endt, ws);
  crf_final<<<1, 64, 0, stream>>>(ws, out);
}

// Round 3
// 1492.579 us; speedup vs baseline: 1.3091x; 1.3091x over previous
//
#include <hip/hip_runtime.h>
#include <hip/hip_bf16.h>

#define B_ 64
#define S_ 2048
#define T_ 256

typedef _Float16 half2_t __attribute__((ext_vector_type(2)));

__device__ __forceinline__ float fdot2f(half2_t a, half2_t b, float c) {
  return __builtin_amdgcn_fdot2(a, b, c, false);
}

__device__ __forceinline__ half2_t pack2(float a, float b) {
  return __builtin_bit_cast(half2_t, __builtin_amdgcn_cvt_pkrtz(a, b));
}

template <int CTRL>
__device__ __forceinline__ float dpp_add(float v) {
  const int t = __builtin_amdgcn_update_dpp(0, __builtin_bit_cast(int, v), CTRL, 0xF, 0xF, true);
  return v + __builtin_bit_cast(float, t);
}
template <int CTRL>
__device__ __forceinline__ float dpp_max(float v) {
  const int t = __builtin_amdgcn_update_dpp(0, __builtin_bit_cast(int, v), CTRL, 0xF, 0xF, true);
  return fmaxf(v, __builtin_bit_cast(float, t));
}

// lgkm-only barrier: LDS visibility without draining in-flight global prefetch
__device__ __forceinline__ void wg_barrier() {
  __builtin_amdgcn_sched_barrier(0);
  asm volatile("s_waitcnt lgkmcnt(0)" ::: "memory");
  __builtin_amdgcn_s_barrier();
  asm volatile("" ::: "memory");
  __builtin_amdgcn_sched_barrier(0);
}

// ---------------- numerator score: ws[b] ----------------
__global__ void crf_score(const float* __restrict__ em, const int* __restrict__ tags,
                          const int* __restrict__ mask, const float* __restrict__ trans,
                          const float* __restrict__ startt, const float* __restrict__ endt,
                          float* __restrict__ ws) {
  const int b = blockIdx.x;
  const int t = threadIdx.x;  // 256
  const int* tg = tags + b * S_;
  const int* mk = mask + b * S_;
  const float* eb = em + (size_t)b * S_ * T_;

  float sc = 0.f;
  int msum = 0;
  for (int s = t; s < S_; s += 256) {
    const int tag = tg[s];
    const int m = mk[s];
    msum += m;
    const float e = eb[(size_t)s * T_ + tag];
    if (s == 0) {
      sc += startt[tag] + e;
    } else {
      const int pt = tg[s - 1];
      sc += (trans[tag * T_ + pt] + e) * (float)m;
    }
  }
#pragma unroll
  for (int off = 32; off > 0; off >>= 1) {
    sc += __shfl_down(sc, off);
    msum += __shfl_down(msum, off);
  }
  __shared__ float ssc[4];
  __shared__ int smc[4];
  const int wv = t >> 6, ln = t & 63;
  if (ln == 0) { ssc[wv] = sc; smc[wv] = msum; }
  __syncthreads();
  if (t == 0) {
    const float s4 = (ssc[0] + ssc[1]) + (ssc[2] + ssc[3]);
    const int m4 = smc[0] + smc[1] + smc[2] + smc[3];
    const int last = tg[m4 - 1];
    ws[b] = s4 + endt[last];
  }
}

// ---------------- forward algorithm (log Z): ws[64+b] ----------------
// 512 threads: thread (g = tid>>3, p = tid&7) owns j = 4g..4g+3, i = 32p..32p+31.
// W tile (32x4 fp16) in 64 VGPRs. alpha stored UNNORMALIZED (bounded) in fp16 LDS;
// previous step's max applied post-dot (scalars commute through the matvec), so the
// max-reduce is off the critical path and one barrier/step suffices.
__global__ __launch_bounds__(512, 2) void crf_forward(
    const float* __restrict__ em, const float* __restrict__ trans,
    const float* __restrict__ startt, const float* __restrict__ endt,
    float* __restrict__ ws) {
  const int b = blockIdx.x;
  const int tid = threadIdx.x;
  const int g = tid >> 3;   // 0..63  (j = 4g + c)
  const int p = tid & 7;    // 0..7   (i = 32p .. 32p+31)
  const int wv = tid >> 6;  // wave 0..7
  const float* eb = em + (size_t)b * S_ * T_;

  // a blocks: 8 blocks of 64B at 112B stride (28 half2) -> 8 addrs hit disjoint bank quads
  __shared__ __align__(16) half2_t aP[2][224];
  __shared__ __align__(16) float ebuf[2][8][T_];  // staged exp(emissions), 8 rows/chunk
  __shared__ float wred[2][8];                    // per-wave maxes (double-buffered)
  __shared__ float fsum[8];

  // --- one-time: W tile into regs: w2[qr][c] = (W[32p+2qr][4g+c], W[32p+2qr+1][4g+c])
  half2_t w2[16][4];
  const int i0 = p * 32;
#pragma unroll
  for (int qr = 0; qr < 16; ++qr)
#pragma unroll
    for (int c = 0; c < 4; ++c) {
      const int j = 4 * g + c;
      const float x0 = __expf(trans[(i0 + 2 * qr) * T_ + j]);
      const float x1 = __expf(trans[(i0 + 2 * qr + 1) * T_ + j]);
      w2[qr][c] = pack2(x0, x1);
    }

  // --- init: al0 = start + em[0] (replicated across p), global max m0
  const float4 st4 = *(const float4*)(startt + 4 * g);
  const float4 e04 = *(const float4*)(eb + 4 * g);
  float al[4] = {st4.x + e04.x, st4.y + e04.y, st4.z + e04.z, st4.w + e04.w};
  float lm = fmaxf(fmaxf(al[0], al[1]), fmaxf(al[2], al[3]));
  lm = dpp_max<0xB1>(lm);   // quad xor1
  lm = dpp_max<0x4E>(lm);   // quad xor2
  lm = dpp_max<0x141>(lm);  // row_half_mirror (8-lane)
  lm = dpp_max<0x140>(lm);  // row_mirror (16-lane)
  lm = fmaxf(lm, __shfl_xor(lm, 16));
  lm = fmaxf(lm, __shfl_xor(lm, 32));
  if ((tid & 63) == 0) fsum[wv] = lm;
  __syncthreads();
  float m0 = fsum[0];
#pragma unroll
  for (int k = 1; k < 8; ++k) m0 = fmaxf(m0, fsum[k]);
  float c_run = m0;

  float xf[4];
#pragma unroll
  for (int c = 0; c < 4; ++c) xf[c] = __expf(al[c] - m0);  // max == 1 exactly
  if (p == 0) {
    const half2_t lo = pack2(xf[0], xf[1]);
    const half2_t hi = pack2(xf[2], xf[3]);
    union { half2_t h[2]; unsigned long long u; } uu; uu.h[0] = lo; uu.h[1] = hi;
    *(unsigned long long*)&aP[1][(g >> 3) * 28 + ((2 * g) & 15)] = uu.u;
  }
  // stage chunk 0 (rows 1..8), pre-exponentiated
  const int col = (tid & 63) * 4;
  {
    float4 f = *(const float4*)(eb + (size_t)(1 + wv) * T_ + col);
    f.x = __expf(f.x); f.y = __expf(f.y); f.z = __expf(f.z); f.w = __expf(f.w);
    *(float4*)&ebuf[0][wv][col] = f;
  }
  if (tid < 8) wred[1][tid] = 1.0f;  // max(x0) == 1
  __syncthreads();
  float4 pre = *(const float4*)(eb + (size_t)(9 + wv) * T_ + col);

  int cur = 0;
  for (int s = 1; s < S_; ++s) {
    const int rb = s & 1, wb = rb ^ 1;
    const int sc = (s - 1) & 7;
    // previous step's normalizer (off critical path: reduce finished last step)
    const float4 wr0 = *(const float4*)&wred[rb][0];
    const float4 wr1 = *(const float4*)&wred[rb][4];
    const float m = fmaxf(fmaxf(fmaxf(wr0.x, wr0.y), fmaxf(wr0.z, wr0.w)),
                          fmaxf(fmaxf(wr1.x, wr1.y), fmaxf(wr1.z, wr1.w)));
    const float rin = __builtin_amdgcn_rcpf(m);
    const float4 E4 = *(const float4*)&ebuf[cur][sc][4 * g];  // exp(em) staged

    // ---- dot: z'[c] = sum_{i in block p} x[i] * W[i][4g+c]
    const float4* af = (const float4*)((const half2_t*)aP[rb] + p * 28);
    float accA[4] = {0.f, 0.f, 0.f, 0.f}, accB[4] = {0.f, 0.f, 0.f, 0.f};
#pragma unroll
    for (int q = 0; q < 4; ++q) {
      const float4 blk = af[q];
      const half2_t v0 = __builtin_bit_cast(half2_t, blk.x);
      const half2_t v1 = __builtin_bit_cast(half2_t, blk.y);
      const half2_t v2 = __builtin_bit_cast(half2_t, blk.z);
      const half2_t v3 = __builtin_bit_cast(half2_t, blk.w);
#pragma unroll
      for (int c = 0; c < 4; ++c) {
        accA[c] = fdot2f(v0, w2[4 * q + 0][c], accA[c]);
        accB[c] = fdot2f(v1, w2[4 * q + 1][c], accB[c]);
        accA[c] = fdot2f(v2, w2[4 * q + 2][c], accA[c]);
        accB[c] = fdot2f(v3, w2[4 * q + 3][c], accB[c]);
      }
    }
    // ---- reduce over 8 i-blocks (lane bits 0..2) in the VALU pipe (DPP)
    float z[4];
#pragma unroll
    for (int c = 0; c < 4; ++c) {
      float t = accA[c] + accB[c];
      t = dpp_add<0xB1>(t);
      t = dpp_add<0x4E>(t);
      t = dpp_add<0x141>(t);
      z[c] = t;
    }
    // ---- x = z' * rin * E / 256 (bounded ~7e3: fp16-safe)
    const float rs = rin * 0.00390625f;
#pragma unroll
    for (int c = 0; c < 4; ++c) xf[c] = z[c] * rs;
    xf[0] *= E4.x; xf[1] *= E4.y; xf[2] *= E4.z; xf[3] *= E4.w;
    // ---- this step's max (consumed next step)
    float mx = fmaxf(fmaxf(xf[0], xf[1]), fmaxf(xf[2], xf[3]));
    mx = dpp_max<0x140>(mx);             // covers lane bit 3 (p-replicated values)
    mx = fmaxf(mx, __shfl_xor(mx, 16));
    mx = fmaxf(mx, __shfl_xor(mx, 32));
    if ((tid & 63) == 0) wred[wb][wv] = mx;
    if (p == 0) {
      const half2_t lo = pack2(xf[0], xf[1]);
      const half2_t hi = pack2(xf[2], xf[3]);
      union { half2_t h[2]; unsigned long long u; } uu; uu.h[0] = lo; uu.h[1] = hi;
      *(unsigned long long*)&aP[wb][(g >> 3) * 28 + ((2 * g) & 15)] = uu.u;
    }
    c_run += 5.545177444479562f - __logf(rin);  // ln(256) - ln(rin)
    // ---- chunk staging every 8 steps (exp applied here, amortized)
    if (sc == 7) {
      const int nxt = cur ^ 1;
      float4 f = pre;
      f.x = __expf(f.x); f.y = __expf(f.y); f.z = __expf(f.z); f.w = __expf(f.w);
      *(float4*)&ebuf[nxt][wv][col] = f;
      const int ck2 = ((s - 1) >> 3) + 2;
      if (ck2 < S_ / 8) {
        int row = 1 + ck2 * 8 + wv;
        if (row > S_ - 1) row = S_ - 1;
        pre = *(const float4*)(eb + (size_t)row * T_ + col);
      }
      cur = nxt;
    }
    wg_barrier();
  }

  // ---- epilogue: log_z = c_run + log(sum_j x[j] * exp(end[j]))
  const float4 en4 = *(const float4*)(endt + 4 * g);
  float fin = 0.f;
  if (p == 0)
    fin = xf[0] * __expf(en4.x) + xf[1] * __expf(en4.y) +
          xf[2] * __expf(en4.z) + xf[3] * __expf(en4.w);
  fin = dpp_add<0xB1>(fin);
  fin = dpp_add<0x4E>(fin);
  fin = dpp_add<0x141>(fin);
  fin = dpp_add<0x140>(fin);
  fin += __shfl_xor(fin, 16);
  fin += __shfl_xor(fin, 32);
  if ((tid & 63) == 0) fsum[wv] = fin;
  __syncthreads();
  if (tid == 0) {
    float tot = 0.f;
#pragma unroll
    for (int k = 0; k < 8; ++k) tot += fsum[k];
    ws[64 + b] = c_run + __logf(tot);
  }
}

// ---------------- final: mean_b(score - logZ) ----------------
__global__ void crf_final(const float* __restrict__ ws, float* __restrict__ out) {
  const int t = threadIdx.x;  // 64
  float v = ws[t] - ws[64 + t];
#pragma unroll
  for (int off = 1; off <= 32; off <<= 1) v += __shfl_xor(v, off);
  if (t == 0) out[0] = v * (1.0f / 64.0f);
}

extern "C" void kernel_launch(void* const* d_in, const int* in_sizes, int n_in,
                              void* d_out, int out_size, void* d_ws, size_t ws_size,
                              hipStream_t stream) {
  const float* em = (const float*)d_in[0];
  const int* tags = (const int*)d_in[1];
  const int* mask = (const int*)d_in[2];
  const float* trans = (const float*)d_in[3];
  const float* startt = (const float*)d_in[4];
  const float* endt = (const float*)d_in[5];
  float* out = (float*)d_out;
  float* ws = (float*)d_ws;

  crf_score<<<B_, 256, 0, stream>>>(em, tags, mask, trans, startt, endt, ws);
  crf_forward<<<B_, 512, 0, stream>>>(em, trans, startt, endt, ws);
  crf_final<<<1, 64, 0, stream>>>(ws, out);
}

// Round 4
// 1436.481 us; speedup vs baseline: 1.3603x; 1.0391x over previous
//
#include <hip/hip_runtime.h>
#include <hip/hip_bf16.h>

#define B_ 64
#define S_ 2048
#define T_ 256

typedef _Float16 half2_t __attribute__((ext_vector_type(2)));

__device__ __forceinline__ float fdot2f(half2_t a, half2_t b, float c) {
  return __builtin_amdgcn_fdot2(a, b, c, false);
}

__device__ __forceinline__ half2_t pack2(float a, float b) {
  return __builtin_bit_cast(half2_t, __builtin_amdgcn_cvt_pkrtz(a, b));
}

template <int CTRL>
__device__ __forceinline__ float dpp_add(float v) {
  const int t = __builtin_amdgcn_update_dpp(0, __builtin_bit_cast(int, v), CTRL, 0xF, 0xF, true);
  return v + __builtin_bit_cast(float, t);
}
template <int CTRL>
__device__ __forceinline__ float dpp_max(float v) {
  const int t = __builtin_amdgcn_update_dpp(0, __builtin_bit_cast(int, v), CTRL, 0xF, 0xF, true);
  return fmaxf(v, __builtin_bit_cast(float, t));
}

// lgkm-only barrier: LDS visibility without draining in-flight global prefetch
__device__ __forceinline__ void wg_barrier() {
  __builtin_amdgcn_sched_barrier(0);
  asm volatile("s_waitcnt lgkmcnt(0)" ::: "memory");
  __builtin_amdgcn_s_barrier();
  asm volatile("" ::: "memory");
  __builtin_amdgcn_sched_barrier(0);
}

// ---------------- numerator score: ws[b] ----------------
__global__ void crf_score(const float* __restrict__ em, const int* __restrict__ tags,
                          const int* __restrict__ mask, const float* __restrict__ trans,
                          const float* __restrict__ startt, const float* __restrict__ endt,
                          float* __restrict__ ws) {
  const int b = blockIdx.x;
  const int t = threadIdx.x;  // 256
  const int* tg = tags + b * S_;
  const int* mk = mask + b * S_;
  const float* eb = em + (size_t)b * S_ * T_;

  float sc = 0.f;
  int msum = 0;
  for (int s = t; s < S_; s += 256) {
    const int tag = tg[s];
    const int m = mk[s];
    msum += m;
    const float e = eb[(size_t)s * T_ + tag];
    if (s == 0) {
      sc += startt[tag] + e;
    } else {
      const int pt = tg[s - 1];
      sc += (trans[tag * T_ + pt] + e) * (float)m;
    }
  }
#pragma unroll
  for (int off = 32; off > 0; off >>= 1) {
    sc += __shfl_down(sc, off);
    msum += __shfl_down(msum, off);
  }
  __shared__ float ssc[4];
  __shared__ int smc[4];
  const int wv = t >> 6, ln = t & 63;
  if (ln == 0) { ssc[wv] = sc; smc[wv] = msum; }
  __syncthreads();
  if (t == 0) {
    const float s4 = (ssc[0] + ssc[1]) + (ssc[2] + ssc[3]);
    const int m4 = smc[0] + smc[1] + smc[2] + smc[3];
    const int last = tg[m4 - 1];
    ws[b] = s4 + endt[last];
  }
}

// ---------------- forward algorithm (log Z): ws[64+b] ----------------
// 512 threads: thread (jg = tid>>2, p = tid&3) owns j = {2jg, 2jg+1}, i = [64p, 64p+64).
// W tile (64x2 fp16) in 64 VGPRs. alpha fp16 in LDS (512B/buf), 16B units rotated by
// 2p mod 8 so the 4 i-block reads hit distinct bank quads. Unnormalized-but-bounded
// storage: prev-step max applied post-dot; max reduced only to 16-lane partials before
// the barrier (no pre-barrier ds_swizzle chain) and finished by next step's reader.
__global__ __launch_bounds__(512, 2) void crf_forward(
    const float* __restrict__ em, const float* __restrict__ trans,
    const float* __restrict__ startt, const float* __restrict__ endt,
    float* __restrict__ ws) {
  const int b = blockIdx.x;
  const int tid = threadIdx.x;
  const int jg = tid >> 2;  // 0..127 (j = 2jg + c)
  const int p = tid & 3;    // 0..3   (i = 64p .. 64p+63)
  const int wv = tid >> 6;  // wave 0..7
  const float* eb = em + (size_t)b * S_ * T_;

  __shared__ __align__(16) unsigned char aPb[2][512];  // alpha fp16, rotated 16B units
  __shared__ __align__(16) float ebuf[2][8][T_];       // staged exp(emissions)
  __shared__ float wred32[2][32];                      // per-16-lane-group maxes
  __shared__ float fsum[8];

  // --- one-time: W tile into regs: w2[q][c] = (W[64p+2q][2jg+c], W[64p+2q+1][2jg+c])
  half2_t w2[32][2];
  const int i0 = p * 64;
#pragma unroll
  for (int q = 0; q < 32; ++q)
#pragma unroll
    for (int c = 0; c < 2; ++c) {
      const int j = 2 * jg + c;
      const float x0 = __expf(trans[(i0 + 2 * q) * T_ + j]);
      const float x1 = __expf(trans[(i0 + 2 * q + 1) * T_ + j]);
      w2[q][c] = pack2(x0, x1);
    }

  // a-read unit offsets (rotated): logical unit r of block p at ((r+2p)&7)*16
  int roff[8];
#pragma unroll
  for (int r = 0; r < 8; ++r) roff[r] = ((r + 2 * p) & 7) * 16;
  const unsigned char* ab0 = aPb[0] + p * 128;
  const unsigned char* ab1 = aPb[1] + p * 128;
  // writer address for jg (byte jg*4 logical): block wp, unit wu rotated, off (jg&3)*4
  const int wp = jg >> 5;
  const int wbyte = wp * 128 + ((((jg >> 2) & 7) + 2 * wp) & 7) * 16 + (jg & 3) * 4;
  unsigned char* wp0 = aPb[0] + wbyte;
  unsigned char* wp1 = aPb[1] + wbyte;

  // --- init: al0 = start + em[0] (replicated across p), global max m0
  const float2 st2 = *(const float2*)(startt + 2 * jg);
  const float2 e02 = *(const float2*)(eb + 2 * jg);
  float al[2] = {st2.x + e02.x, st2.y + e02.y};
  float lm = fmaxf(al[0], al[1]);
  lm = dpp_max<0x141>(lm);  // bit2 (8-mirror)
  lm = dpp_max<0x140>(lm);  // bit3 (16-mirror)
  lm = fmaxf(lm, __shfl_xor(lm, 16));
  lm = fmaxf(lm, __shfl_xor(lm, 32));
  if ((tid & 63) == 0) fsum[wv] = lm;
  __syncthreads();
  float m0 = fsum[0];
#pragma unroll
  for (int k = 1; k < 8; ++k) m0 = fmaxf(m0, fsum[k]);
  float c_run = m0;

  float xf[2];
  xf[0] = __expf(al[0] - m0);
  xf[1] = __expf(al[1] - m0);
  if (p == 0) *(half2_t*)wp1 = pack2(xf[0], xf[1]);
  if (tid < 32) wred32[1][tid] = 1.0f;  // max(x0) == 1 exactly
  // stage chunk 0 (rows 1..8), pre-exponentiated
  const int col = (tid & 63) * 4;
  {
    float4 f = *(const float4*)(eb + (size_t)(1 + wv) * T_ + col);
    f.x = __expf(f.x); f.y = __expf(f.y); f.z = __expf(f.z); f.w = __expf(f.w);
    *(float4*)&ebuf[0][wv][col] = f;
  }
  __syncthreads();
  float4 pre = *(const float4*)(eb + (size_t)(9 + wv) * T_ + col);

  int cur = 0;
  for (int s = 1; s < S_; ++s) {
    const int rb = s & 1;
    const int sc = (s - 1) & 7;
    // ---- previous step's normalizer: 32 partials -> full max (off critical path)
    const float4 wr = *(const float4*)&wred32[rb][(tid & 7) * 4];
    float m = fmaxf(fmaxf(wr.x, wr.y), fmaxf(wr.z, wr.w));
    m = dpp_max<0xB1>(m);
    m = dpp_max<0x4E>(m);
    m = dpp_max<0x141>(m);
    const float rin = __builtin_amdgcn_rcpf(m);
    const float2 E2 = *(const float2*)&ebuf[cur][sc][2 * jg];

    // ---- dot: z[c] = sum_{i in block p} x[i] * W[i][2jg+c]
    const unsigned char* ab = rb ? ab1 : ab0;
    float a0A = 0.f, a0B = 0.f, a1A = 0.f, a1B = 0.f;
#pragma unroll
    for (int r = 0; r < 8; ++r) {
      const float4 blk = *(const float4*)(ab + roff[r]);
      const half2_t v0 = __builtin_bit_cast(half2_t, blk.x);
      const half2_t v1 = __builtin_bit_cast(half2_t, blk.y);
      const half2_t v2 = __builtin_bit_cast(half2_t, blk.z);
      const half2_t v3 = __builtin_bit_cast(half2_t, blk.w);
      a0A = fdot2f(v0, w2[4 * r + 0][0], a0A);
      a1A = fdot2f(v0, w2[4 * r + 0][1], a1A);
      a0B = fdot2f(v1, w2[4 * r + 1][0], a0B);
      a1B = fdot2f(v1, w2[4 * r + 1][1], a1B);
      a0A = fdot2f(v2, w2[4 * r + 2][0], a0A);
      a1A = fdot2f(v2, w2[4 * r + 2][1], a1A);
      a0B = fdot2f(v3, w2[4 * r + 3][0], a0B);
      a1B = fdot2f(v3, w2[4 * r + 3][1], a1B);
    }
    float z0 = a0A + a0B, z1 = a1A + a1B;
    // reduce over 4 i-blocks (lane bits 0,1)
    z0 = dpp_add<0xB1>(z0); z0 = dpp_add<0x4E>(z0);
    z1 = dpp_add<0xB1>(z1); z1 = dpp_add<0x4E>(z1);
    // ---- x = z * rin * E / 256 (bounded ~7e3: fp16-safe)
    const float rs = rin * 0.00390625f;
    xf[0] = z0 * (rs * E2.x);
    xf[1] = z1 * (rs * E2.y);
    // ---- this step's max: reduce to 16-lane partials only (no ds_swizzle)
    float mx = fmaxf(xf[0], xf[1]);
    mx = dpp_max<0x141>(mx);  // bit2
    mx = dpp_max<0x140>(mx);  // bit3
    if ((tid & 15) == 0) wred32[rb ^ 1][tid >> 4] = mx;
    if (p == 0) *(half2_t*)(rb ? wp0 : wp1) = pack2(xf[0], xf[1]);
    c_run += 5.545177444479562f - __logf(rin);  // ln(256) - ln(rin)
    // ---- chunk staging every 8 steps
    if (sc == 7) {
      const int nxt = cur ^ 1;
      float4 f = pre;
      f.x = __expf(f.x); f.y = __expf(f.y); f.z = __expf(f.z); f.w = __expf(f.w);
      *(float4*)&ebuf[nxt][wv][col] = f;
      const int ck2 = ((s - 1) >> 3) + 2;
      if (ck2 < S_ / 8) {
        int row = 1 + ck2 * 8 + wv;
        if (row > S_ - 1) row = S_ - 1;
        pre = *(const float4*)(eb + (size_t)row * T_ + col);
      }
      cur = nxt;
    }
    wg_barrier();
  }

  // ---- epilogue: log_z = c_run + log(sum_j x[j] * exp(end[j]))
  const float2 en2 = *(const float2*)(endt + 2 * jg);
  float fin = 0.f;
  if (p == 0) fin = xf[0] * __expf(en2.x) + xf[1] * __expf(en2.y);
  fin = dpp_add<0xB1>(fin);
  fin = dpp_add<0x4E>(fin);
  fin = dpp_add<0x141>(fin);
  fin = dpp_add<0x140>(fin);
  fin += __shfl_xor(fin, 16);
  fin += __shfl_xor(fin, 32);
  if ((tid & 63) == 0) fsum[wv] = fin;
  __syncthreads();
  if (tid == 0) {
    float tot = 0.f;
#pragma unroll
    for (int k = 0; k < 8; ++k) tot += fsum[k];
    ws[64 + b] = c_run + __logf(tot);
  }
}

// ---------------- final: mean_b(score - logZ) ----------------
__global__ void crf_final(const float* __restrict__ ws, float* __restrict__ out) {
  const int t = threadIdx.x;  // 64
  float v = ws[t] - ws[64 + t];
#pragma unroll
  for (int off = 1; off <= 32; off <<= 1) v += __shfl_xor(v, off);
  if (t == 0) out[0] = v * (1.0f / 64.0f);
}

extern "C" void kernel_launch(void* const* d_in, const int* in_sizes, int n_in,
                              void* d_out, int out_size, void* d_ws, size_t ws_size,
                              hipStream_t stream) {
  const float* em = (const float*)d_in[0];
  const int* tags = (const int*)d_in[1];
  const int* mask = (const int*)d_in[2];
  const float* trans = (const float*)d_in[3];
  const float* startt = (const float*)d_in[4];
  const float* endt = (const float*)d_in[5];
  float* out = (float*)d_out;
  float* ws = (float*)d_ws;

  crf_score<<<B_, 256, 0, stream>>>(em, tags, mask, trans, startt, endt, ws);
  crf_forward<<<B_, 512, 0, stream>>>(em, trans, startt, endt, ws);
  crf_final<<<1, 64, 0, stream>>>(ws, out);
}

// Round 6
// 1258.613 us; speedup vs baseline: 1.5525x; 1.1413x over previous
//
#include <hip/hip_runtime.h>
#include <hip/hip_bf16.h>

#define B_ 64
#define S_ 2048
#define T_ 256

typedef _Float16 half2_t __attribute__((ext_vector_type(2)));

__device__ __forceinline__ half2_t pack2(float a, float b) {
  return __builtin_bit_cast(half2_t, __builtin_amdgcn_cvt_pkrtz(a, b));
}
__device__ __forceinline__ half2_t swap16(half2_t v) {
  const unsigned u = __builtin_bit_cast(unsigned, v);
  return __builtin_bit_cast(half2_t, __builtin_amdgcn_alignbit(u, u, 16));
}
template <int CTRL>
__device__ __forceinline__ float dpp_max(float v) {
  const int t = __builtin_amdgcn_update_dpp(0, __builtin_bit_cast(int, v), CTRL, 0xF, 0xF, true);
  return fmaxf(v, __builtin_bit_cast(float, t));
}
template <int CTRL>
__device__ __forceinline__ float dpp_add(float v) {
  const int t = __builtin_amdgcn_update_dpp(0, __builtin_bit_cast(int, v), CTRL, 0xF, 0xF, true);
  return v + __builtin_bit_cast(float, t);
}
template <int CTRL>
__device__ __forceinline__ half2_t dpp_addpk(half2_t v) {
  const int t = __builtin_amdgcn_update_dpp(0, __builtin_bit_cast(int, v), CTRL, 0xF, 0xF, true);
  return v + __builtin_bit_cast(half2_t, t);
}

// lgkm-only barrier: LDS visibility without draining in-flight global prefetch
__device__ __forceinline__ void wg_barrier() {
  __builtin_amdgcn_sched_barrier(0);
  asm volatile("s_waitcnt lgkmcnt(0)" ::: "memory");
  __builtin_amdgcn_s_barrier();
  asm volatile("" ::: "memory");
  __builtin_amdgcn_sched_barrier(0);
}

// ---------------- numerator score: ws[b] ----------------
__global__ void crf_score(const float* __restrict__ em, const int* __restrict__ tags,
                          const int* __restrict__ mask, const float* __restrict__ trans,
                          const float* __restrict__ startt, const float* __restrict__ endt,
                          float* __restrict__ ws) {
  const int b = blockIdx.x;
  const int t = threadIdx.x;  // 256
  const int* tg = tags + b * S_;
  const int* mk = mask + b * S_;
  const float* eb = em + (size_t)b * S_ * T_;

  float sc = 0.f;
  int msum = 0;
  for (int s = t; s < S_; s += 256) {
    const int tag = tg[s];
    const int m = mk[s];
    msum += m;
    const float e = eb[(size_t)s * T_ + tag];
    if (s == 0) {
      sc += startt[tag] + e;
    } else {
      const int pt = tg[s - 1];
      sc += (trans[tag * T_ + pt] + e) * (float)m;
    }
  }
#pragma unroll
  for (int off = 32; off > 0; off >>= 1) {
    sc += __shfl_down(sc, off);
    msum += __shfl_down(msum, off);
  }
  __shared__ float ssc[4];
  __shared__ int smc[4];
  const int wv = t >> 6, ln = t & 63;
  if (ln == 0) { ssc[wv] = sc; smc[wv] = msum; }
  __syncthreads();
  if (t == 0) {
    const float s4 = (ssc[0] + ssc[1]) + (ssc[2] + ssc[3]);
    const int m4 = smc[0] + smc[1] + smc[2] + smc[3];
    const int last = tg[m4 - 1];
    ws[b] = s4 + endt[last];
  }
}

// ---------------- forward algorithm (log Z): ws[64+b] ----------------
// 512 threads: thread (jg = tid>>3, ig = tid&7): j = 4jg+{0..3}, i in [32ig, 32ig+32).
// Inner product via v_pk_fma_f16 (dual-accumulator swapped-pair packing, no splats).
// alpha fp16 in LDS (512B/buf), block-rotated 16B units for conflict-freedom.
// Renorm: EXACT 1-stale power-of-two scale: rs = 2^(-e(max x_{s-1})-7), e clamped
// >= -17 so rs fits fp16. Bounds: M*rs in [2^-7,2^-6] => x <= 283*2^-6*245 ~ 1080,
// fp16 accums <= 16*1080*1.105 ~ 1.9e4 < 65504. Bookkeeping via integer k_run (exact).
__global__ __launch_bounds__(512, 2) void crf_forward(
    const float* __restrict__ em, const float* __restrict__ trans,
    const float* __restrict__ startt, const float* __restrict__ endt,
    float* __restrict__ ws) {
  const int b = blockIdx.x;
  const int tid = threadIdx.x;
  const int jg = tid >> 3;  // 0..63
  const int ig = tid & 7;   // 0..7
  const int wv = tid >> 6;  // wave 0..7
  const float* eb = em + (size_t)b * S_ * T_;

  __shared__ __align__(16) unsigned char aPb[2][512];  // alpha fp16, rotated 16B units
  __shared__ __align__(16) float ebuf[2][8][T_];       // staged exp(emissions), fp32
  __shared__ float wredq[2][32];                       // 16-lane-group maxes, 2-slot ring
  __shared__ float fsum[8];

  // --- one-time: W tiles, swapped-pair packed:
  // wA[q][h] = (W[i0][j0], W[i0+1][j0+1]),  wB[q][h] = (W[i0][j0+1], W[i0+1][j0])
  // where i0 = 32ig+2q, j0 = 4jg+2h.
  half2_t wA[16][2], wB[16][2];
#pragma unroll
  for (int q = 0; q < 16; ++q) {
    const int i0 = 32 * ig + 2 * q;
#pragma unroll
    for (int h = 0; h < 2; ++h) {
      const int j0 = 4 * jg + 2 * h;
      const float w00 = __expf(trans[i0 * T_ + j0]);
      const float w01 = __expf(trans[i0 * T_ + j0 + 1]);
      const float w10 = __expf(trans[(i0 + 1) * T_ + j0]);
      const float w11 = __expf(trans[(i0 + 1) * T_ + j0 + 1]);
      wA[q][h] = pack2(w00, w11);
      wB[q][h] = pack2(w01, w10);
    }
  }

  // a-read offsets: logical unit r of block ig at phys unit 4ig + ((r+ig)&3)
  int roff[4];
#pragma unroll
  for (int r = 0; r < 4; ++r) roff[r] = (4 * ig + ((r + ig) & 3)) * 16;
  // writer: logical unit u = jg>>1 (blk = u>>2), byte offset within unit = (jg&1)*8
  const int w_u = jg >> 1;
  const int w_blk = w_u >> 2;
  const int wbyte = (4 * w_blk + (((w_u & 3) + w_blk) & 3)) * 16 + (jg & 1) * 8;

  // --- init: al0 = start + em[0] (replicated across ig), exact max m0
  const float4 st4 = *(const float4*)(startt + 4 * jg);
  const float4 e04 = *(const float4*)(eb + 4 * jg);
  float al[4] = {st4.x + e04.x, st4.y + e04.y, st4.z + e04.z, st4.w + e04.w};
  float lm = fmaxf(fmaxf(al[0], al[1]), fmaxf(al[2], al[3]));
  lm = dpp_max<0xB1>(lm);
  lm = dpp_max<0x4E>(lm);
  lm = dpp_max<0x141>(lm);
  lm = dpp_max<0x140>(lm);
  lm = fmaxf(lm, __shfl_xor(lm, 16));
  lm = fmaxf(lm, __shfl_xor(lm, 32));
  if ((tid & 63) == 0) fsum[wv] = lm;
  __syncthreads();
  float m0 = fsum[0];
#pragma unroll
  for (int k = 1; k < 8; ++k) m0 = fmaxf(m0, fsum[k]);

  half2_t xpk0 = pack2(__expf(al[0] - m0), __expf(al[1] - m0));
  half2_t xpk1 = pack2(__expf(al[2] - m0), __expf(al[3] - m0));
  if (ig == 0) {
    union { half2_t h[2]; unsigned long long u; } uu;
    uu.h[0] = xpk0; uu.h[1] = xpk1;
    *(unsigned long long*)(aPb[1] + wbyte) = uu.u;
  }
  if (tid < 32) wredq[0][tid] = 1.0f;  // max(x0) == 1 exactly
  // stage chunk 0 (rows 1..8)
  const int col = (tid & 63) * 4;
  {
    float4 f = *(const float4*)(eb + (size_t)(1 + wv) * T_ + col);
    f.x = __expf(f.x); f.y = __expf(f.y); f.z = __expf(f.z); f.w = __expf(f.w);
    *(float4*)&ebuf[0][wv][col] = f;
  }
  __syncthreads();
  float4 pre = *(const float4*)(eb + (size_t)(9 + wv) * T_ + col);

  int cur = 0;
  int k_run = 0;
  for (int s = 1; s < S_; ++s) {
    const int rb = s & 1;
    const int sc = (s - 1) & 7;
    // ---- exact 1-stale normalizer: max of x_{s-1} (dep chain hidden under the dot)
    const float4 wr = *(const float4*)&wredq[(s + 1) & 1][(tid & 7) * 4];
    float mh = fmaxf(fmaxf(wr.x, wr.y), fmaxf(wr.z, wr.w));
    mh = dpp_max<0xB1>(mh);
    mh = dpp_max<0x4E>(mh);
    mh = dpp_max<0x141>(mh);
    int ue = (int)(__builtin_bit_cast(unsigned, mh) >> 23) - 127;
    ue = (ue < -17) ? -17 : ue;  // rs <= 2^10: fp16-safe under any pathology
    const float rs_f = __builtin_bit_cast(float, (unsigned)((120 - ue) << 23));  // 2^(-ue-7)
    const half2_t rs_pk = pack2(rs_f, rs_f);

    // ---- dot: z[4jg+c] partial over i-block ig, via pk_fma (full-rate)
    const unsigned char* ab = aPb[rb];
    half2_t accA0 = {}, accA1 = {}, accB0 = {}, accB1 = {};
#pragma unroll
    for (int r = 0; r < 4; ++r) {
      const float4 blk = *(const float4*)(ab + roff[r]);
      const half2_t a0 = __builtin_bit_cast(half2_t, blk.x);
      const half2_t a1 = __builtin_bit_cast(half2_t, blk.y);
      const half2_t a2 = __builtin_bit_cast(half2_t, blk.z);
      const half2_t a3 = __builtin_bit_cast(half2_t, blk.w);
      accA0 = __builtin_elementwise_fma(a0, wA[4 * r + 0][0], accA0);
      accA1 = __builtin_elementwise_fma(a0, wA[4 * r + 0][1], accA1);
      accB0 = __builtin_elementwise_fma(a0, wB[4 * r + 0][0], accB0);
      accB1 = __builtin_elementwise_fma(a0, wB[4 * r + 0][1], accB1);
      accA0 = __builtin_elementwise_fma(a1, wA[4 * r + 1][0], accA0);
      accA1 = __builtin_elementwise_fma(a1, wA[4 * r + 1][1], accA1);
      accB0 = __builtin_elementwise_fma(a1, wB[4 * r + 1][0], accB0);
      accB1 = __builtin_elementwise_fma(a1, wB[4 * r + 1][1], accB1);
      accA0 = __builtin_elementwise_fma(a2, wA[4 * r + 2][0], accA0);
      accA1 = __builtin_elementwise_fma(a2, wA[4 * r + 2][1], accA1);
      accB0 = __builtin_elementwise_fma(a2, wB[4 * r + 2][0], accB0);
      accB1 = __builtin_elementwise_fma(a2, wB[4 * r + 2][1], accB1);
      accA0 = __builtin_elementwise_fma(a3, wA[4 * r + 3][0], accA0);
      accA1 = __builtin_elementwise_fma(a3, wA[4 * r + 3][1], accA1);
      accB0 = __builtin_elementwise_fma(a3, wB[4 * r + 3][0], accB0);
      accB1 = __builtin_elementwise_fma(a3, wB[4 * r + 3][1], accB1);
    }
    // (z[j0], z[j0+1]) = accA + swap16(accB)
    half2_t zpk0 = accA0 + swap16(accB0);
    half2_t zpk1 = accA1 + swap16(accB1);

    // ---- scale by exact pow2 and emission, THEN reduce (keeps fp16 in range)
    const float4 E4 = *(const float4*)&ebuf[cur][sc][4 * jg];
    const half2_t Ep0 = pack2(E4.x, E4.y);
    const half2_t Ep1 = pack2(E4.z, E4.w);
    xpk0 = (zpk0 * rs_pk) * Ep0;
    xpk1 = (zpk1 * rs_pk) * Ep1;
    // ---- butterfly over 8 i-blocks (lane bits 0..2), packed fp16
    xpk0 = dpp_addpk<0xB1>(xpk0);  xpk1 = dpp_addpk<0xB1>(xpk1);
    xpk0 = dpp_addpk<0x4E>(xpk0);  xpk1 = dpp_addpk<0x4E>(xpk1);
    xpk0 = dpp_addpk<0x141>(xpk0); xpk1 = dpp_addpk<0x141>(xpk1);

    // ---- this step's max -> 16-lane partials (consumed next step)
    float c0 = (float)xpk0.x, c1 = (float)xpk0.y, c2 = (float)xpk1.x, c3 = (float)xpk1.y;
    float mx = fmaxf(fmaxf(c0, c1), fmaxf(c2, c3));
    mx = dpp_max<0x140>(mx);  // bit3 (bits 0-2 already uniform post-butterfly)
    if ((tid & 15) == 0) wredq[s & 1][tid >> 4] = mx;
    // ---- store new alpha (fp16 pair-packed, rotated layout)
    if (ig == 0) {
      union { half2_t h[2]; unsigned long long u; } uu;
      uu.h[0] = xpk0; uu.h[1] = xpk1;
      *(unsigned long long*)(aPb[rb ^ 1] + wbyte) = uu.u;
    }
    k_run += ue + 7;  // exact integer bookkeeping of the applied 2^-(ue+7) scales
    // ---- chunk staging every 8 steps
    if (sc == 7) {
      const int nxt = cur ^ 1;
      float4 f = pre;
      f.x = __expf(f.x); f.y = __expf(f.y); f.z = __expf(f.z); f.w = __expf(f.w);
      *(float4*)&ebuf[nxt][wv][col] = f;
      const int ck2 = ((s - 1) >> 3) + 2;
      if (ck2 < S_ / 8) {
        int row = 1 + ck2 * 8 + wv;
        if (row > S_ - 1) row = S_ - 1;
        pre = *(const float4*)(eb + (size_t)row * T_ + col);
      }
      cur = nxt;
    }
    wg_barrier();
  }

  // ---- epilogue: log_z = m0 + k_run*ln2 + log(sum_j x[j] * exp(end[j]))
  const float4 en4 = *(const float4*)(endt + 4 * jg);
  float fin = 0.f;
  if (ig == 0) {
    fin = (float)xpk0.x * __expf(en4.x) + (float)xpk0.y * __expf(en4.y) +
          (float)xpk1.x * __expf(en4.z) + (float)xpk1.y * __expf(en4.w);
  }
  fin = dpp_add<0xB1>(fin);
  fin = dpp_add<0x4E>(fin);
  fin = dpp_add<0x141>(fin);
  fin = dpp_add<0x140>(fin);
  fin += __shfl_xor(fin, 16);
  fin += __shfl_xor(fin, 32);
  if ((tid & 63) == 0) fsum[wv] = fin;
  __syncthreads();
  if (tid == 0) {
    float tot = 0.f;
#pragma unroll
    for (int k = 0; k < 8; ++k) tot += fsum[k];
    ws[64 + b] = m0 + (float)k_run * 0.6931471805599453f + __logf(tot);
  }
}

// ---------------- final: mean_b(score - logZ) ----------------
__global__ void crf_final(const float* __restrict__ ws, float* __restrict__ out) {
  const int t = threadIdx.x;  // 64
  float v = ws[t] - ws[64 + t];
#pragma unroll
  for (int off = 1; off <= 32; off <<= 1) v += __shfl_xor(v, off);
  if (t == 0) out[0] = v * (1.0f / 64.0f);
}

extern "C" void kernel_launch(void* const* d_in, const int* in_sizes, int n_in,
                              void* d_out, int out_size, void* d_ws, size_t ws_size,
                              hipStream_t stream) {
  const float* em = (const float*)d_in[0];
  const int* tags = (const int*)d_in[1];
  const int* mask = (const int*)d_in[2];
  const float* trans = (const float*)d_in[3];
  const float* startt = (const float*)d_in[4];
  const float* endt = (const float*)d_in[5];
  float* out = (float*)d_out;
  float* ws = (float*)d_ws;

  crf_score<<<B_, 256, 0, stream>>>(em, tags, mask, trans, startt, endt, ws);
  crf_forward<<<B_, 512, 0, stream>>>(em, trans, startt, endt, ws);
  crf_final<<<1, 64, 0, stream>>>(ws, out);
}

// Round 8
// 1249.570 us; speedup vs baseline: 1.5637x; 1.0072x over previous
//
#include <hip/hip_runtime.h>
#include <hip/hip_bf16.h>

#define B_ 64
#define S_ 2048
#define T_ 256

typedef _Float16 half2_t __attribute__((ext_vector_type(2)));

__device__ __forceinline__ float fdot2f(half2_t a, half2_t b, float c) {
  return __builtin_amdgcn_fdot2(a, b, c, false);
}
__device__ __forceinline__ half2_t pack2(float a, float b) {
  return __builtin_bit_cast(half2_t, __builtin_amdgcn_cvt_pkrtz(a, b));
}
template <int CTRL>
__device__ __forceinline__ float dpp_max(float v) {
  const int t = __builtin_amdgcn_update_dpp(0, __builtin_bit_cast(int, v), CTRL, 0xF, 0xF, true);
  return fmaxf(v, __builtin_bit_cast(float, t));
}
template <int CTRL>
__device__ __forceinline__ float dpp_add(float v) {
  const int t = __builtin_amdgcn_update_dpp(0, __builtin_bit_cast(int, v), CTRL, 0xF, 0xF, true);
  return v + __builtin_bit_cast(float, t);
}

// lgkm-only barrier: LDS visibility without draining in-flight global prefetch
__device__ __forceinline__ void wg_barrier() {
  __builtin_amdgcn_sched_barrier(0);
  asm volatile("s_waitcnt lgkmcnt(0)" ::: "memory");
  __builtin_amdgcn_s_barrier();
  asm volatile("" ::: "memory");
  __builtin_amdgcn_sched_barrier(0);
}

// ---------------- numerator score: ws[b] ----------------
__global__ void crf_score(const float* __restrict__ em, const int* __restrict__ tags,
                          const int* __restrict__ mask, const float* __restrict__ trans,
                          const float* __restrict__ startt, const float* __restrict__ endt,
                          float* __restrict__ ws) {
  const int b = blockIdx.x;
  const int t = threadIdx.x;  // 256
  const int* tg = tags + b * S_;
  const int* mk = mask + b * S_;
  const float* eb = em + (size_t)b * S_ * T_;

  float sc = 0.f;
  int msum = 0;
  for (int s = t; s < S_; s += 256) {
    const int tag = tg[s];
    const int m = mk[s];
    msum += m;
    const float e = eb[(size_t)s * T_ + tag];
    if (s == 0) {
      sc += startt[tag] + e;
    } else {
      const int pt = tg[s - 1];
      sc += (trans[tag * T_ + pt] + e) * (float)m;
    }
  }
#pragma unroll
  for (int off = 32; off > 0; off >>= 1) {
    sc += __shfl_down(sc, off);
    msum += __shfl_down(msum, off);
  }
  __shared__ float ssc[4];
  __shared__ int smc[4];
  const int wv = t >> 6, ln = t & 63;
  if (ln == 0) { ssc[wv] = sc; smc[wv] = msum; }
  __syncthreads();
  if (t == 0) {
    const float s4 = (ssc[0] + ssc[1]) + (ssc[2] + ssc[3]);
    const int m4 = smc[0] + smc[1] + smc[2] + smc[3];
    const int last = tg[m4 - 1];
    ws[b] = s4 + endt[last];
  }
}

// ---------------- forward algorithm (log Z): ws[64+b] ----------------
// 256 threads (4 waves): thread (jg = tid>>3 -> j = 8jg..8jg+7, ig = tid&7 ->
// i in [32ig, 32ig+32)). W: 256 f16 = 128 VGPRs. alpha f16 LDS 512B/buf,
// rotated 16B units. 128 fdot2/thread with f32 accum.
// Renorm: exact 1-stale power-of-two from the POST-E max of the STORED x
// (memoryless: max(x_s)*rs_{s+1} in [2^-8,2^-7) each step — no oscillator;
// pre-E max was round 7's instability). Integer k_run bookkeeping is exact.
// Bounds: x <= 283*2*2^-8*E <= ~600 (fp16-safe); max(x) >= ~2^-17.
__global__ __launch_bounds__(256, 1) void crf_forward(
    const float* __restrict__ em, const float* __restrict__ trans,
    const float* __restrict__ startt, const float* __restrict__ endt,
    float* __restrict__ ws) {
  const int b = blockIdx.x;
  const int tid = threadIdx.x;  // 0..255
  const int jg = tid >> 3;      // 0..31
  const int ig = tid & 7;       // 0..7
  const int wv = tid >> 6;      // wave 0..3
  const int lane = tid & 63;
  const float* eb = em + (size_t)b * S_ * T_;

  __shared__ __align__(16) unsigned char aPb[2][512];  // alpha f16, rotated 16B units
  __shared__ __align__(16) float ebuf[2][8][T_];       // staged exp(emissions)
  __shared__ float wredq[2][16];                       // per-16-lane maxes, 2-slot ring
  __shared__ float fsum[4];

  // --- one-time: W tile (32 i x 8 j) as 128 half2: w2[q][h] = (W[i0][j], W[i0+1][j])
  half2_t w2[16][8];
#pragma unroll
  for (int q = 0; q < 16; ++q) {
    const int i0 = 32 * ig + 2 * q;
#pragma unroll
    for (int h = 0; h < 8; ++h) {
      const int j = 8 * jg + h;
      w2[q][h] = pack2(__expf(trans[i0 * T_ + j]), __expf(trans[(i0 + 1) * T_ + j]));
    }
  }

  // a-read offsets: logical 16B unit r of block ig at phys unit 4ig + ((r+ig)&3)
  int roff[4];
#pragma unroll
  for (int r = 0; r < 4; ++r) roff[r] = (4 * ig + ((r + ig) & 3)) * 16;
  // writer byte (16B for j=8jg..8jg+7): block w_blk = jg>>2, local unit jg&3
  const int w_blk = jg >> 2;
  const int wbyte = (4 * w_blk + (((jg & 3) + w_blk) & 3)) * 16;

  // --- init: al0 = start + em[0] (replicated across ig), exact max m0
  const float4 sa = *(const float4*)(startt + 8 * jg);
  const float4 sb = *(const float4*)(startt + 8 * jg + 4);
  const float4 ea = *(const float4*)(eb + 8 * jg);
  const float4 eb4 = *(const float4*)(eb + 8 * jg + 4);
  float al[8] = {sa.x + ea.x, sa.y + ea.y, sa.z + ea.z, sa.w + ea.w,
                 sb.x + eb4.x, sb.y + eb4.y, sb.z + eb4.z, sb.w + eb4.w};
  float lm = al[0];
#pragma unroll
  for (int h = 1; h < 8; ++h) lm = fmaxf(lm, al[h]);
  lm = dpp_max<0xB1>(lm);
  lm = dpp_max<0x4E>(lm);
  lm = dpp_max<0x141>(lm);
  lm = dpp_max<0x140>(lm);
  lm = fmaxf(lm, __shfl_xor(lm, 16));
  lm = fmaxf(lm, __shfl_xor(lm, 32));
  if (lane == 0) fsum[wv] = lm;
  __syncthreads();
  float m0 = fmaxf(fmaxf(fsum[0], fsum[1]), fmaxf(fsum[2], fsum[3]));

  float xf[8];
#pragma unroll
  for (int h = 0; h < 8; ++h) xf[h] = __expf(al[h] - m0);
  if (ig == 0) {
    union { half2_t h[4]; float4 f; } uu;
    uu.h[0] = pack2(xf[0], xf[1]); uu.h[1] = pack2(xf[2], xf[3]);
    uu.h[2] = pack2(xf[4], xf[5]); uu.h[3] = pack2(xf[6], xf[7]);
    *(float4*)(aPb[1] + wbyte) = uu.f;
  }
  if (tid < 16) wredq[0][tid] = 1.0f;  // max(x0) == 1 exactly (post-store semantics)
  // stage chunk 0 (rows 1..8): wave wv does chunk-rows {2wv, 2wv+1}
  const int col = lane * 4;
  {
    float4 f0 = *(const float4*)(eb + (size_t)(1 + 2 * wv) * T_ + col);
    float4 f1 = *(const float4*)(eb + (size_t)(2 + 2 * wv) * T_ + col);
    f0.x = __expf(f0.x); f0.y = __expf(f0.y); f0.z = __expf(f0.z); f0.w = __expf(f0.w);
    f1.x = __expf(f1.x); f1.y = __expf(f1.y); f1.z = __expf(f1.z); f1.w = __expf(f1.w);
    *(float4*)&ebuf[0][2 * wv][col] = f0;
    *(float4*)&ebuf[0][2 * wv + 1][col] = f1;
  }
  __syncthreads();
  float4 pre0 = *(const float4*)(eb + (size_t)(9 + 2 * wv) * T_ + col);
  float4 pre1 = *(const float4*)(eb + (size_t)(10 + 2 * wv) * T_ + col);

  int cur = 0;
  int k_run = 0;
  for (int s = 1; s < S_; ++s) {
    const int rb = s & 1;
    const int sc = (s - 1) & 7;
    // ---- 1-stale normalizer from max(x_{s-1}) (off critical path)
    const float4 wr = *(const float4*)&wredq[(s + 1) & 1][(tid & 3) * 4];
    float mh = fmaxf(fmaxf(wr.x, wr.y), fmaxf(wr.z, wr.w));
    mh = dpp_max<0xB1>(mh);
    mh = dpp_max<0x4E>(mh);
    int ue = (int)(__builtin_bit_cast(unsigned, mh) >> 23) - 127;
    ue = (ue < -20) ? -20 : ue;
    const float rs_f = __builtin_bit_cast(float, (unsigned)((119 - ue) << 23));  // 2^(-ue-8)

    // ---- dot: acc[h] = sum_{i in block ig} a[i] * W[i][8jg+h]  (f32 accum)
    const unsigned char* ab = aPb[rb];
    const float4 blk0 = *(const float4*)(ab + roff[0]);
    const float4 blk1 = *(const float4*)(ab + roff[1]);
    const float4 blk2 = *(const float4*)(ab + roff[2]);
    const float4 blk3 = *(const float4*)(ab + roff[3]);
    float acc[8] = {0.f, 0.f, 0.f, 0.f, 0.f, 0.f, 0.f, 0.f};
    const float4 blks[4] = {blk0, blk1, blk2, blk3};
#pragma unroll
    for (int r = 0; r < 4; ++r) {
      const half2_t a0 = __builtin_bit_cast(half2_t, blks[r].x);
      const half2_t a1 = __builtin_bit_cast(half2_t, blks[r].y);
      const half2_t a2 = __builtin_bit_cast(half2_t, blks[r].z);
      const half2_t a3 = __builtin_bit_cast(half2_t, blks[r].w);
#pragma unroll
      for (int h = 0; h < 8; ++h) {
        acc[h] = fdot2f(a0, w2[4 * r + 0][h], acc[h]);
        acc[h] = fdot2f(a1, w2[4 * r + 1][h], acc[h]);
        acc[h] = fdot2f(a2, w2[4 * r + 2][h], acc[h]);
        acc[h] = fdot2f(a3, w2[4 * r + 3][h], acc[h]);
      }
    }
    // ---- butterfly over 8 i-blocks (lane bits 0..2), f32
#pragma unroll
    for (int h = 0; h < 8; ++h) {
      acc[h] = dpp_add<0xB1>(acc[h]);
      acc[h] = dpp_add<0x4E>(acc[h]);
      acc[h] = dpp_add<0x141>(acc[h]);
    }
    // ---- x = acc * rs * E in ALL lanes (post-E max is what keeps renorm stable)
    const float4 E0 = *(const float4*)&ebuf[cur][sc][8 * jg];
    const float4 E1 = *(const float4*)&ebuf[cur][sc][8 * jg + 4];
    xf[0] = acc[0] * rs_f * E0.x; xf[1] = acc[1] * rs_f * E0.y;
    xf[2] = acc[2] * rs_f * E0.z; xf[3] = acc[3] * rs_f * E0.w;
    xf[4] = acc[4] * rs_f * E1.x; xf[5] = acc[5] * rs_f * E1.y;
    xf[6] = acc[6] * rs_f * E1.z; xf[7] = acc[7] * rs_f * E1.w;
    // ---- this step's max of stored x -> 16-lane partials (consumed next step)
    float mx = fmaxf(fmaxf(fmaxf(xf[0], xf[1]), fmaxf(xf[2], xf[3])),
                     fmaxf(fmaxf(xf[4], xf[5]), fmaxf(xf[6], xf[7])));
    mx = dpp_max<0x140>(mx);  // bit3 (bits 0..2 uniform post-butterfly)
    if ((lane & 15) == 0) wredq[s & 1][wv * 4 + (lane >> 4)] = mx;
    // ---- writers: pack to f16, single b128 store
    if (ig == 0) {
      union { half2_t h[4]; float4 f; } uu;
      uu.h[0] = pack2(xf[0], xf[1]); uu.h[1] = pack2(xf[2], xf[3]);
      uu.h[2] = pack2(xf[4], xf[5]); uu.h[3] = pack2(xf[6], xf[7]);
      *(float4*)(aPb[rb ^ 1] + wbyte) = uu.f;
    }
    k_run += ue + 8;  // exact integer bookkeeping of applied 2^-(ue+8) scales
    // ---- chunk staging every 8 steps
    if (sc == 7) {
      const int nxt = cur ^ 1;
      float4 f0 = pre0, f1 = pre1;
      f0.x = __expf(f0.x); f0.y = __expf(f0.y); f0.z = __expf(f0.z); f0.w = __expf(f0.w);
      f1.x = __expf(f1.x); f1.y = __expf(f1.y); f1.z = __expf(f1.z); f1.w = __expf(f1.w);
      *(float4*)&ebuf[nxt][2 * wv][col] = f0;
      *(float4*)&ebuf[nxt][2 * wv + 1][col] = f1;
      const int ck2 = ((s - 1) >> 3) + 2;
      if (ck2 < S_ / 8) {
        int row0 = 1 + ck2 * 8 + 2 * wv;
        int row1 = row0 + 1;
        if (row0 > S_ - 1) row0 = S_ - 1;
        if (row1 > S_ - 1) row1 = S_ - 1;
        pre0 = *(const float4*)(eb + (size_t)row0 * T_ + col);
        pre1 = *(const float4*)(eb + (size_t)row1 * T_ + col);
      }
      cur = nxt;
    }
    wg_barrier();
  }

  // ---- epilogue: log_z = m0 + k_run*ln2 + log(sum_j x[j] * exp(end[j]))
  float fin = 0.f;
  if (ig == 0) {
    const float4 en0 = *(const float4*)(endt + 8 * jg);
    const float4 en1 = *(const float4*)(endt + 8 * jg + 4);
    fin = xf[0] * __expf(en0.x) + xf[1] * __expf(en0.y) +
          xf[2] * __expf(en0.z) + xf[3] * __expf(en0.w) +
          xf[4] * __expf(en1.x) + xf[5] * __expf(en1.y) +
          xf[6] * __expf(en1.z) + xf[7] * __expf(en1.w);
  }
  fin = dpp_add<0xB1>(fin);
  fin = dpp_add<0x4E>(fin);
  fin = dpp_add<0x141>(fin);
  fin = dpp_add<0x140>(fin);
  fin += __shfl_xor(fin, 16);
  fin += __shfl_xor(fin, 32);
  __syncthreads();  // reuse fsum safely
  if (lane == 0) fsum[wv] = fin;
  __syncthreads();
  if (tid == 0) {
    const float tot = (fsum[0] + fsum[1]) + (fsum[2] + fsum[3]);
    ws[64 + b] = m0 + (float)k_run * 0.6931471805599453f + __logf(tot);
  }
}

// ---------------- final: mean_b(score - logZ) ----------------
__global__ void crf_final(const float* __restrict__ ws, float* __restrict__ out) {
  const int t = threadIdx.x;  // 64
  float v = ws[t] - ws[64 + t];
#pragma unroll
  for (int off = 1; off <= 32; off <<= 1) v += __shfl_xor(v, off);
  if (t == 0) out[0] = v * (1.0f / 64.0f);
}

extern "C" void kernel_launch(void* const* d_in, const int* in_sizes, int n_in,
                              void* d_out, int out_size, void* d_ws, size_t ws_size,
                              hipStream_t stream) {
  const float* em = (const float*)d_in[0];
  const int* tags = (const int*)d_in[1];
  const int* mask = (const int*)d_in[2];
  const float* trans = (const float*)d_in[3];
  const float* startt = (const float*)d_in[4];
  const float* endt = (const float*)d_in[5];
  float* out = (float*)d_out;
  float* ws = (float*)d_ws;

  crf_score<<<B_, 256, 0, stream>>>(em, tags, mask, trans, startt, endt, ws);
  crf_forward<<<B_, 256, 0, stream>>>(em, trans, startt, endt, ws);
  crf_final<<<1, 64, 0, stream>>>(ws, out);
}